// Round 1
// baseline (130.949 us; speedup 1.0000x reference)
//
#include <hip/hip_runtime.h>
#include <hip/hip_bf16.h>

#define Bn 4096
#define Dk 1024
#define EPSF 1e-7f

typedef unsigned short ushort_t;
typedef __bf16 bf16x8 __attribute__((ext_vector_type(8)));
typedef float f32x4 __attribute__((ext_vector_type(4)));

__device__ __forceinline__ unsigned pack_bf16_2(float a, float b) {
    __hip_bfloat162 h = __float22bfloat162_rn(make_float2(a, b));
    unsigned u;
    __builtin_memcpy(&u, &h, 4);
    return u;
}

__device__ __forceinline__ void async_copy16(const void* g, void* l) {
    __builtin_amdgcn_global_load_lds((__attribute__((address_space(1))) void*)(uintptr_t)g,
                                     (__attribute__((address_space(3))) void*)l, 16, 0, 0);
}

// -------- Kernel 1: L2-normalize rows -> bf16; exact f32 diag dot; zero sums --------
__global__ __launch_bounds__(256)
void nrm_kernel(const float4* __restrict__ left, const float4* __restrict__ right,
                uint2* __restrict__ lnb, uint2* __restrict__ rnb,
                float* __restrict__ diag, float* __restrict__ rowsum,
                float* __restrict__ colsum)
{
    const int row = blockIdx.x;
    const int t = threadIdx.x;
    const int idx = row * (Dk / 4) + t;
    const float4 l = left[idx];
    const float4 r = right[idx];
    float sl = l.x * l.x + l.y * l.y + l.z * l.z + l.w * l.w;
    float sr = r.x * r.x + r.y * r.y + r.z * r.z + r.w * r.w;
    float slr = l.x * r.x + l.y * r.y + l.z * r.z + l.w * r.w;
    #pragma unroll
    for (int off = 1; off < 64; off <<= 1) {
        sl += __shfl_xor(sl, off);
        sr += __shfl_xor(sr, off);
        slr += __shfl_xor(slr, off);
    }
    __shared__ float red[3][4];
    const int wave = t >> 6, lane = t & 63;
    if (lane == 0) { red[0][wave] = sl; red[1][wave] = sr; red[2][wave] = slr; }
    __syncthreads();
    sl = red[0][0] + red[0][1] + red[0][2] + red[0][3];
    sr = red[1][0] + red[1][1] + red[1][2] + red[1][3];
    const float invl = 1.0f / sqrtf(fmaxf(sl, EPSF));
    const float invr = 1.0f / sqrtf(fmaxf(sr, EPSF));
    lnb[idx] = make_uint2(pack_bf16_2(l.x * invl, l.y * invl),
                          pack_bf16_2(l.z * invl, l.w * invl));
    rnb[idx] = make_uint2(pack_bf16_2(r.x * invr, r.y * invr),
                          pack_bf16_2(r.z * invr, r.w * invr));
    if (t == 0) {
        const float d = red[2][0] + red[2][1] + red[2][2] + red[2][3];
        diag[row] = d * invl * invr;
        rowsum[row] = 0.f;
        colsum[row] = 0.f;
    }
}

// -------- Kernel 2: S = ln . rn^T via bf16 MFMA; epilogue accumulates exp sums --------
// 128x128 tile, BK=32, 4 waves in 2x2, each wave 4x4 of 16x16x32 MFMA.
__global__ __launch_bounds__(256, 2)
void gemm_sm_kernel(const ushort_t* __restrict__ lnb, const ushort_t* __restrict__ rnb,
                    const float* __restrict__ temp,
                    float* __restrict__ rowsum, float* __restrict__ colsum)
{
    __shared__ __align__(16) ushort_t As[128 * 32];
    __shared__ __align__(16) ushort_t Bs[128 * 32];

    const int tid = threadIdx.x;
    const int wave = tid >> 6;
    const int lane = tid & 63;
    const int bm0 = blockIdx.y * 128;
    const int bn0 = blockIdx.x * 128;

    // staging: wave w covers tile rows [w*32, w*32+32); 2 wave-instructions of 16 rows each
    const int srow = wave * 32 + (lane >> 2);
    const int scol = (lane & 3) * 8;  // ushort index within 32-wide row
    const ushort_t* gA0 = lnb + (size_t)(bm0 + srow) * Dk + scol;
    const ushort_t* gA1 = gA0 + 16 * Dk;
    const ushort_t* gB0 = rnb + (size_t)(bn0 + srow) * Dk + scol;
    const ushort_t* gB1 = gB0 + 16 * Dk;
    ushort_t* lA0 = &As[(wave * 32) * 32];
    ushort_t* lA1 = lA0 + 16 * 32;
    ushort_t* lB0 = &Bs[(wave * 32) * 32];
    ushort_t* lB1 = lB0 + 16 * 32;

    const int wm = (wave & 1) * 64;
    const int wn = (wave >> 1) * 64;
    const int quad = lane >> 4;
    const int r16 = lane & 15;

    f32x4 acc[4][4];
    #pragma unroll
    for (int i = 0; i < 4; ++i)
        #pragma unroll
        for (int j = 0; j < 4; ++j)
            acc[i][j] = (f32x4){0.f, 0.f, 0.f, 0.f};

    int aoff[4], boff[4];
    #pragma unroll
    for (int i = 0; i < 4; ++i) {
        aoff[i] = (wm + i * 16 + r16) * 32 + quad * 8;
        boff[i] = (wn + i * 16 + r16) * 32 + quad * 8;
    }

    for (int k0 = 0; k0 < Dk; k0 += 32) {
        async_copy16(gA0 + k0, lA0);
        async_copy16(gA1 + k0, lA1);
        async_copy16(gB0 + k0, lB0);
        async_copy16(gB1 + k0, lB1);
        __syncthreads();
        bf16x8 af[4], bfv[4];
        #pragma unroll
        for (int i = 0; i < 4; ++i) af[i] = *(const bf16x8*)(&As[aoff[i]]);
        #pragma unroll
        for (int i = 0; i < 4; ++i) bfv[i] = *(const bf16x8*)(&Bs[boff[i]]);
        #pragma unroll
        for (int mi = 0; mi < 4; ++mi)
            #pragma unroll
            for (int ni = 0; ni < 4; ++ni)
                acc[mi][ni] = __builtin_amdgcn_mfma_f32_16x16x32_bf16(
                    af[mi], bfv[ni], acc[mi][ni], 0, 0, 0);
        __syncthreads();
    }

    // epilogue: p = exp(scale*s - scale)  (|s|<=1 so scale is a valid max bound)
    const float scale = __expf(temp[0]);
    #pragma unroll
    for (int mi = 0; mi < 4; ++mi)
        #pragma unroll
        for (int ni = 0; ni < 4; ++ni)
            #pragma unroll
            for (int r = 0; r < 4; ++r)
                acc[mi][ni][r] = __expf(scale * acc[mi][ni][r] - scale);

    // C/D layout: col = lane&15, row = quad*4 + reg
    // row sums: reduce over ni and the 16 lanes of the quad-group
    #pragma unroll
    for (int mi = 0; mi < 4; ++mi) {
        #pragma unroll
        for (int r = 0; r < 4; ++r) {
            float v = acc[mi][0][r] + acc[mi][1][r] + acc[mi][2][r] + acc[mi][3][r];
            v += __shfl_xor(v, 1);
            v += __shfl_xor(v, 2);
            v += __shfl_xor(v, 4);
            v += __shfl_xor(v, 8);
            if (r16 == 0)
                atomicAdd(&rowsum[bm0 + wm + mi * 16 + quad * 4 + r], v);
        }
    }
    // col sums: reduce over mi,r in-lane, then across the 4 quads
    #pragma unroll
    for (int ni = 0; ni < 4; ++ni) {
        float v = 0.f;
        #pragma unroll
        for (int mi = 0; mi < 4; ++mi)
            #pragma unroll
            for (int r = 0; r < 4; ++r)
                v += acc[mi][ni][r];
        v += __shfl_xor(v, 16);
        v += __shfl_xor(v, 32);
        if (quad == 0)
            atomicAdd(&colsum[bn0 + wn + ni * 16 + r16], v);
    }
}

// -------- Kernel 3: final scalar loss --------
__global__ __launch_bounds__(256)
void loss_kernel(const float* __restrict__ diag, const float* __restrict__ rowsum,
                 const float* __restrict__ colsum, const float* __restrict__ temp,
                 float* __restrict__ out)
{
    const int t = threadIdx.x;
    const float scale = __expf(temp[0]);
    float dL = 0.f, dR = 0.f;
    for (int i = t; i < Bn; i += 256) {
        const float e = __expf(scale * (diag[i] - 1.0f));
        dL += e / rowsum[i];
        dR += e / colsum[i];
    }
    #pragma unroll
    for (int off = 1; off < 64; off <<= 1) {
        dL += __shfl_xor(dL, off);
        dR += __shfl_xor(dR, off);
    }
    __shared__ float rd[2][4];
    const int wave = t >> 6, lane = t & 63;
    if (lane == 0) { rd[0][wave] = dL; rd[1][wave] = dR; }
    __syncthreads();
    if (t == 0) {
        dL = rd[0][0] + rd[0][1] + rd[0][2] + rd[0][3];
        dR = rd[1][0] + rd[1][1] + rd[1][2] + rd[1][3];
        const float logeps = logf(EPSF);
        const float log1m = logf(1.0f - EPSF);
        const float lossL = -(dL * log1m + ((float)Bn - dL) * logeps);
        const float lossR = -(dR * log1m + ((float)Bn - dR) * logeps);
        out[0] = (lossL + lossR) * 0.5f / (float)Bn;
    }
}

extern "C" void kernel_launch(void* const* d_in, const int* in_sizes, int n_in,
                              void* d_out, int out_size, void* d_ws, size_t ws_size,
                              hipStream_t stream) {
    (void)in_sizes; (void)n_in; (void)out_size; (void)ws_size;
    const float* left = (const float*)d_in[0];
    const float* right = (const float*)d_in[1];
    const float* temp = (const float*)d_in[2];

    char* ws = (char*)d_ws;
    ushort_t* lnb = (ushort_t*)ws;                                        // 8 MiB
    ushort_t* rnb = (ushort_t*)(ws + (size_t)Bn * Dk * sizeof(ushort_t)); // 8 MiB
    float* diag = (float*)(ws + (size_t)Bn * Dk * 4);
    float* rowsum = diag + Bn;
    float* colsum = rowsum + Bn;

    nrm_kernel<<<Bn, 256, 0, stream>>>((const float4*)left, (const float4*)right,
                                       (uint2*)lnb, (uint2*)rnb, diag, rowsum, colsum);
    dim3 g2(Bn / 128, Bn / 128);
    gemm_sm_kernel<<<g2, 256, 0, stream>>>(lnb, rnb, temp, rowsum, colsum);
    loss_kernel<<<1, 256, 0, stream>>>(diag, rowsum, colsum, temp, (float*)d_out);
}